// Round 4
// baseline (195.197 us; speedup 1.0000x reference)
//
#include <hip/hip_runtime.h>
#include <hip/hip_bf16.h>

#define NA    90000
#define NGT   256
#define KNMS  2000
#define RPAD  2048          // padded NMS rows (multiple of 64)
#define NBINS 4096
#define CMAX  4096          // compact buffer capacity
#define IMGSZ 1600.0f

// ---------------- ws layout (bytes) ----------------
// keys  : 0        .. 720000   (u64[90000])
// hist  : 720000   .. 736384   (u32[4096])
// ctr   : 736384   .. 736400   (u32[4])   [0]=compact count, [1]=bin B
// buf   : 736400   .. 769168   (u64[4096])
// cand  : 769168   .. 801936   (float4[2048])
// mask  : 801936   .. 1326224  (u64[2048*32] == u32[2048*64] little-endian)

__device__ __forceinline__ float4 compute_local(int k) {
    const float ratios[3] = {0.5f, 1.0f, 2.0f};
    const float scales[3] = {8.0f, 16.0f, 32.0f};
    int r = k / 3, sc = k % 3;
    float b0 = 0.0f, b1 = 0.0f, b2 = 15.0f, b3 = 15.0f;
    float y0 = b0 + 0.5f * (b3 - 1.0f);
    float y1 = b1 + 0.5f * (b2 - 1.0f);
    float y2 = b3 - b1 + 1.0f;
    float y3 = b2 - b0 + 1.0f;
    float wr = rintf(sqrtf(y2 * y3 / ratios[r]));   // jnp.round = half-even = rintf
    float hr = rintf(wr * ratios[r]);
    float a0 = y0 - 0.5f * (wr - 1.0f);
    float a1 = y1 - 0.5f * (hr - 1.0f);
    float a2 = y0 + 0.5f * (wr - 1.0f);
    float a3 = y1 + 0.5f * (hr - 1.0f);
    float ya0 = a0 + 0.5f * (a3 - 1.0f);
    float ya1 = a1 + 0.5f * (a2 - 1.0f);
    float ya2 = a3 - a1 + 1.0f;
    float ya3 = a2 - a0 + 1.0f;
    float w = ya2 * scales[sc];
    float h = ya3 * scales[sc];
    float4 o;
    o.x = ya0 - 0.5f * (w - 1.0f);
    o.y = ya1 - 0.5f * (h - 1.0f);
    o.z = ya0 + 0.5f * (w - 1.0f);
    o.w = ya1 + 0.5f * (h - 1.0f);
    return o;
}

__global__ void k_zero(unsigned int* __restrict__ hist, unsigned int* __restrict__ ctr) {
    int i = blockIdx.x * 256 + threadIdx.x;
    if (i < NBINS) hist[i] = 0u;
    if (i < 4) ctr[i] = 0u;
}

__global__ __launch_bounds__(256) void k_prep(
    const float* __restrict__ true_bx, const float* __restrict__ deltas,
    const float* __restrict__ scores, float* __restrict__ out,
    unsigned long long* __restrict__ keys, unsigned int* __restrict__ hist)
{
    __shared__ float4 gt[NGT];
    int tid = threadIdx.x;
    for (int i = tid; i < NGT; i += 256) gt[i] = ((const float4*)true_bx)[i];
    __syncthreads();

    int a = blockIdx.x * 256 + tid;
    if (a >= NA) return;

    int k  = a % 9;
    int s  = a / 9;
    int ix = s % 100;
    int iy = s / 100;

    float4 loc = compute_local(k);
    float sxv = (float)ix * 16.0f, syv = (float)iy * 16.0f;
    float ax1 = fminf(fmaxf(loc.x + sxv, 0.0f), IMGSZ);
    float ay1 = fminf(fmaxf(loc.y + syv, 0.0f), IMGSZ);
    float ax2 = fminf(fmaxf(loc.z + sxv, 0.0f), IMGSZ);
    float ay2 = fminf(fmaxf(loc.w + syv, 0.0f), IMGSZ);
    float areaA = (ax2 - ax1) * (ay2 - ay1);

    // argmax over 256 GTs, strict > keeps FIRST max (jnp.argmax semantics)
    float best = -1.0f; int bidx = 0;
    #pragma unroll 4
    for (int g = 0; g < NGT; ++g) {
        float4 G = gt[g];
        float areaG = (G.z - G.x) * (G.w - G.y);
        float lx = fmaxf(G.x, ax1), ly = fmaxf(G.y, ay1);
        float rx = fminf(G.z, ax2), ry = fminf(G.w, ay2);
        float iw = fmaxf(rx - lx, 0.0f), ih = fmaxf(ry - ly, 0.0f);
        float inter = iw * ih;
        float iou = inter / (areaG + areaA - inter);
        if (iou > best) { best = iou; bidx = g; }
    }

    float4 G = gt[bidx];
    float scx = (ax1 + ax2) * 0.5f, scy = (ay1 + ay2) * 0.5f;
    float sw = ax2 - ax1, sh = ay2 - ay1;
    float dcx = (G.x + G.z) * 0.5f, dcy = (G.y + G.w) * 0.5f;
    float dw = G.z - G.x, dh = G.w - G.y;
    float t0 = (scx - dcx) / dw;
    float t1 = (scy - dcy) / dh;
    float t2 = logf(sw / dw);
    float t3 = logf(sh / dh);

    float4 d = ((const float4*)deltas)[a];
    float cx = d.x * sw + scx, cy = d.y * sh + scy;
    float w = expf(d.z) * sw, h = expf(d.w) * sh;
    float r0 = fminf(fmaxf(cx - 0.5f * w, 0.0f), IMGSZ);
    float r1 = fminf(fmaxf(cy - 0.5f * h, 0.0f), IMGSZ);
    float r2 = fminf(fmaxf(cx + 0.5f * w, 0.0f), IMGSZ);
    float r3 = fminf(fmaxf(cy + 0.5f * h, 0.0f), IMGSZ);

    float* row = out + (size_t)a * 9;
    row[0] = t0; row[1] = t1; row[2] = t2; row[3] = t3;
    row[4] = r0; row[5] = r1; row[6] = r2; row[7] = r3;
    row[8] = best;

    float sc = scores[a];
    unsigned int b = __float_as_uint(sc);
    unsigned int m = (b & 0x80000000u) ? ~b : (b | 0x80000000u);  // monotone map
    keys[a] = ((unsigned long long)m << 32) | (unsigned long long)(0xFFFFFFFFu - (unsigned int)a);
    int bin = (int)(sc * (float)NBINS);
    bin = bin < 0 ? 0 : (bin > NBINS - 1 ? NBINS - 1 : bin);
    atomicAdd(&hist[bin], 1u);
}

// 64-lane parallel suffix-scan over histogram bins (descending), ballot pick.
__global__ __launch_bounds__(64) void k_findbin(const unsigned int* __restrict__ hist,
                                                unsigned int* __restrict__ ctr) {
    int lane = threadIdx.x;
    unsigned int cum = 0;
    for (int c = 0; c < 64; ++c) {
        int bin = NBINS - 1 - c * 64 - lane;   // lane 0 = highest bin of chunk
        unsigned int v = hist[bin];
        unsigned int s = v;
        #pragma unroll
        for (int d = 1; d < 64; d <<= 1) {
            unsigned int t = __shfl_up(s, d, 64);
            if (lane >= d) s += t;
        }
        unsigned long long ball = __ballot(cum + s >= (unsigned int)KNMS);
        if (ball) {
            int L = __builtin_ctzll(ball);
            if (lane == 0) ctr[1] = (unsigned int)(NBINS - 1 - c * 64 - L);
            return;
        }
        cum += __shfl(s, 63, 64);
    }
    if (lane == 0) ctr[1] = 0u;  // fallback: everything passes
}

__global__ __launch_bounds__(256) void k_compact(
    const float* __restrict__ scores, const unsigned long long* __restrict__ keys,
    unsigned int* __restrict__ ctr, unsigned long long* __restrict__ buf)
{
    int a = blockIdx.x * 256 + threadIdx.x;
    if (a >= NA) return;
    float sc = scores[a];
    int bin = (int)(sc * (float)NBINS);
    bin = bin < 0 ? 0 : (bin > NBINS - 1 ? NBINS - 1 : bin);
    if ((unsigned int)bin >= ctr[1]) {
        unsigned int p = atomicAdd(&ctr[0], 1u);
        if (p < CMAX) buf[p] = keys[a];
    }
}

__global__ __launch_bounds__(1024) void k_sort(
    const unsigned int* __restrict__ ctr, const unsigned long long* __restrict__ buf,
    const float* __restrict__ out, float4* __restrict__ cand)
{
    __shared__ unsigned long long A[CMAX];
    unsigned int M = ctr[0] < (unsigned int)CMAX ? ctr[0] : (unsigned int)CMAX;
    int tid = threadIdx.x;
    for (int i = tid; i < CMAX; i += 1024) A[i] = (i < (int)M) ? buf[i] : 0ull;
    __syncthreads();

    // bitonic sort, DESCENDING (real keys all >= 2^63 > pad 0)
    for (int k = 2; k <= CMAX; k <<= 1) {
        for (int j = k >> 1; j > 0; j >>= 1) {
            for (int e = tid; e < CMAX; e += 1024) {
                int p = e ^ j;
                if (p > e) {
                    unsigned long long x = A[e], y = A[p];
                    bool up = ((e & k) == 0);
                    bool sw = up ? (x < y) : (x > y);
                    if (sw) { A[e] = y; A[p] = x; }
                }
            }
            __syncthreads();
        }
    }

    for (int i = tid; i < RPAD; i += 1024) {
        float4 c = make_float4(0.0f, 0.0f, 0.0f, 0.0f);
        if (i < KNMS && i < (int)M) {
            unsigned int idx = 0xFFFFFFFFu - (unsigned int)(A[i] & 0xFFFFFFFFull);
            const float* row = out + (size_t)idx * 9;
            c = make_float4(row[4], row[5], row[6], row[7]);
        }
        cand[i] = c;
    }
}

__global__ __launch_bounds__(64) void k_mask(
    const float4* __restrict__ cand, unsigned long long* __restrict__ mask)
{
    int rowChunk = blockIdx.x;   // 0..31
    int colChunk = blockIdx.y;   // 0..31
    __shared__ float4 cb[64];
    int t = threadIdx.x;
    cb[t] = cand[colChunk * 64 + t];
    __syncthreads();

    int r = rowChunk * 64 + t;
    unsigned long long m = 0ull;
    if (r < KNMS) {
        float4 R = cand[r];
        float areaR = (R.z - R.x) * (R.w - R.y);
        #pragma unroll 8
        for (int c = 0; c < 64; ++c) {
            int col = colChunk * 64 + c;
            if (col < KNMS && col > r) {
                float4 C = cb[c];
                float areaC = (C.z - C.x) * (C.w - C.y);
                float lx = fmaxf(R.x, C.x), ly = fmaxf(R.y, C.y);
                float rx = fminf(R.z, C.z), ry = fminf(R.w, C.w);
                float iw = fmaxf(rx - lx, 0.0f), ih = fmaxf(ry - ly, 0.0f);
                float inter = iw * ih;
                float iou = inter / (areaR + areaC - inter);
                if (iou > 0.7f) m |= (1ull << c);
            }
        }
    }
    mask[(size_t)r * 32 + colChunk] = m;
}

// Scalar-chain NMS, fully branchless. Per 64-row block the kept/suppressed chain
// is 3 SALU per row (s_bitcmp -> s_cselect_b64 -> s_or_b64). Vector remv updates
// are batched per half-block, off the serial chain (only needed before the NEXT
// block's readlane snapshot).
__device__ __forceinline__ unsigned long long rl64(unsigned int v, int b) {
    return (unsigned long long)(unsigned int)__builtin_amdgcn_readlane((int)v, 2 * b) |
           ((unsigned long long)(unsigned int)__builtin_amdgcn_readlane((int)v, 2 * b + 1) << 32);
}

__global__ __launch_bounds__(64) void k_nms(
    const unsigned int* __restrict__ mask32, float* __restrict__ keep_out)
{
    const int lane = threadIdx.x;
    const unsigned int* base = mask32 + lane;   // lane l owns u32 word l of each row
    unsigned int remv = 0u;
    unsigned int A[32], B[32];
    #pragma unroll
    for (int j = 0; j < 32; ++j) A[j] = base[(size_t)j * 64];
    #pragma unroll
    for (int j = 0; j < 32; ++j) B[j] = base[(size_t)(32 + j) * 64];

    for (int b = 0; b < 32; ++b) {
        unsigned long long cur = rl64(remv, b);
        unsigned long long kb = 0ull;   // kept bits of this block

        // half 0: rows 64b + j (bit j of cur) -- branchless scalar chain
        #pragma unroll
        for (int j = 0; j < 32; ++j) {
            unsigned long long dg = rl64(A[j], b);
            unsigned long long sel = ((cur >> j) & 1ull) ? 0ull : ~0ull;   // s_cselect
            cur |= dg & sel;
            kb |= (1ull << j) & sel;
        }
        // half 0 vector remv update (off-chain)
        #pragma unroll
        for (int j = 0; j < 32; ++j) {
            unsigned int km = (unsigned int)((kb >> j) & 1ull) ? 0xFFFFFFFFu : 0u;
            remv |= A[j] & km;
        }
        // prefetch next block's half 0
        if (b < 31) {
            const unsigned int* nb = base + (size_t)(b + 1) * 64 * 64;
            #pragma unroll
            for (int j = 0; j < 32; ++j) A[j] = nb[(size_t)j * 64];
        }

        // half 1: rows 64b + 32 + j (bit 32+j of cur)
        #pragma unroll
        for (int j = 0; j < 32; ++j) {
            unsigned long long dg = rl64(B[j], b);
            unsigned long long sel = ((cur >> (32 + j)) & 1ull) ? 0ull : ~0ull;
            cur |= dg & sel;
            kb |= (1ull << (32 + j)) & sel;
        }
        #pragma unroll
        for (int j = 0; j < 32; ++j) {
            unsigned int km = (unsigned int)((kb >> (32 + j)) & 1ull) ? 0xFFFFFFFFu : 0u;
            remv |= B[j] & km;
        }
        if (b < 31) {
            const unsigned int* nb = base + (size_t)(b + 1) * 64 * 64 + 32 * 64;
            #pragma unroll
            for (int j = 0; j < 32; ++j) B[j] = nb[(size_t)j * 64];
        }

        int row = b * 64 + lane;
        float kf = ((kb >> lane) & 1ull) ? 1.0f : 0.0f;
        if (row < KNMS) keep_out[row] = kf;
    }
}

extern "C" void kernel_launch(void* const* d_in, const int* in_sizes, int n_in,
                              void* d_out, int out_size, void* d_ws, size_t ws_size,
                              hipStream_t stream) {
    const float* true_bx = (const float*)d_in[2];
    const float* deltas  = (const float*)d_in[3];
    const float* scores  = (const float*)d_in[4];
    float* out = (float*)d_out;

    char* ws = (char*)d_ws;
    unsigned long long* keys = (unsigned long long*)(ws + 0);
    unsigned int*       hist = (unsigned int*)(ws + 720000);
    unsigned int*       ctr  = (unsigned int*)(ws + 736384);
    unsigned long long* buf  = (unsigned long long*)(ws + 736400);
    float4*             cand = (float4*)(ws + 769168);
    unsigned long long* mask = (unsigned long long*)(ws + 801936);
    unsigned int*       mask32 = (unsigned int*)(ws + 801936);

    hipLaunchKernelGGL(k_zero, dim3(16), dim3(256), 0, stream, hist, ctr);
    hipLaunchKernelGGL(k_prep, dim3((NA + 255) / 256), dim3(256), 0, stream,
                       true_bx, deltas, scores, out, keys, hist);
    hipLaunchKernelGGL(k_findbin, dim3(1), dim3(64), 0, stream, hist, ctr);
    hipLaunchKernelGGL(k_compact, dim3((NA + 255) / 256), dim3(256), 0, stream,
                       scores, keys, ctr, buf);
    hipLaunchKernelGGL(k_sort, dim3(1), dim3(1024), 0, stream, ctr, buf, out, cand);
    hipLaunchKernelGGL(k_mask, dim3(32, 32), dim3(64), 0, stream, cand, mask);
    hipLaunchKernelGGL(k_nms, dim3(1), dim3(64), 0, stream, mask32, out + (size_t)NA * 9);
}

// Round 5
// 182.688 us; speedup vs baseline: 1.0685x; 1.0685x over previous
//
#include <hip/hip_runtime.h>
#include <hip/hip_bf16.h>

#define NA    90000
#define NGT   256
#define KNMS  2000
#define RPAD  2048          // padded NMS rows (multiple of 64)
#define NBINS 4096
#define CMAX  4096          // compact buffer capacity
#define IMGSZ 1600.0f

// ---------------- ws layout (bytes) ----------------
// keys  : 0        .. 720000   (u64[90000])
// hist  : 720000   .. 736384   (u32[4096])
// ctr   : 736384   .. 736400   (u32[4])   [0]=compact count, [1]=bin B
// buf   : 736400   .. 769168   (u64[4096])
// cand  : 769168   .. 801936   (float4[2048])
// mask  : 801936   .. 1326224  (u64[2048*32] == u32[2048*64] little-endian)

__device__ __forceinline__ float4 compute_local(int k) {
    const float ratios[3] = {0.5f, 1.0f, 2.0f};
    const float scales[3] = {8.0f, 16.0f, 32.0f};
    int r = k / 3, sc = k % 3;
    float b0 = 0.0f, b1 = 0.0f, b2 = 15.0f, b3 = 15.0f;
    float y0 = b0 + 0.5f * (b3 - 1.0f);
    float y1 = b1 + 0.5f * (b2 - 1.0f);
    float y2 = b3 - b1 + 1.0f;
    float y3 = b2 - b0 + 1.0f;
    float wr = rintf(sqrtf(y2 * y3 / ratios[r]));   // jnp.round = half-even = rintf
    float hr = rintf(wr * ratios[r]);
    float a0 = y0 - 0.5f * (wr - 1.0f);
    float a1 = y1 - 0.5f * (hr - 1.0f);
    float a2 = y0 + 0.5f * (wr - 1.0f);
    float a3 = y1 + 0.5f * (hr - 1.0f);
    float ya0 = a0 + 0.5f * (a3 - 1.0f);
    float ya1 = a1 + 0.5f * (a2 - 1.0f);
    float ya2 = a3 - a1 + 1.0f;
    float ya3 = a2 - a0 + 1.0f;
    float w = ya2 * scales[sc];
    float h = ya3 * scales[sc];
    float4 o;
    o.x = ya0 - 0.5f * (w - 1.0f);
    o.y = ya1 - 0.5f * (h - 1.0f);
    o.z = ya0 + 0.5f * (w - 1.0f);
    o.w = ya1 + 0.5f * (h - 1.0f);
    return o;
}

__global__ void k_zero(unsigned int* __restrict__ hist, unsigned int* __restrict__ ctr) {
    int i = blockIdx.x * 256 + threadIdx.x;
    if (i < NBINS) hist[i] = 0u;
    if (i < 4) ctr[i] = 0u;
}

__global__ __launch_bounds__(256) void k_prep(
    const float* __restrict__ true_bx, const float* __restrict__ deltas,
    const float* __restrict__ scores, float* __restrict__ out,
    unsigned long long* __restrict__ keys, unsigned int* __restrict__ hist)
{
    __shared__ float4 gt[NGT];
    int tid = threadIdx.x;
    for (int i = tid; i < NGT; i += 256) gt[i] = ((const float4*)true_bx)[i];
    __syncthreads();

    int a = blockIdx.x * 256 + tid;
    if (a >= NA) return;

    int k  = a % 9;
    int s  = a / 9;
    int ix = s % 100;
    int iy = s / 100;

    float4 loc = compute_local(k);
    float sxv = (float)ix * 16.0f, syv = (float)iy * 16.0f;
    float ax1 = fminf(fmaxf(loc.x + sxv, 0.0f), IMGSZ);
    float ay1 = fminf(fmaxf(loc.y + syv, 0.0f), IMGSZ);
    float ax2 = fminf(fmaxf(loc.z + sxv, 0.0f), IMGSZ);
    float ay2 = fminf(fmaxf(loc.w + syv, 0.0f), IMGSZ);
    float areaA = (ax2 - ax1) * (ay2 - ay1);

    // argmax over 256 GTs, strict > keeps FIRST max (jnp.argmax semantics)
    float best = -1.0f; int bidx = 0;
    #pragma unroll 4
    for (int g = 0; g < NGT; ++g) {
        float4 G = gt[g];
        float areaG = (G.z - G.x) * (G.w - G.y);
        float lx = fmaxf(G.x, ax1), ly = fmaxf(G.y, ay1);
        float rx = fminf(G.z, ax2), ry = fminf(G.w, ay2);
        float iw = fmaxf(rx - lx, 0.0f), ih = fmaxf(ry - ly, 0.0f);
        float inter = iw * ih;
        float iou = inter / (areaG + areaA - inter);
        if (iou > best) { best = iou; bidx = g; }
    }

    float4 G = gt[bidx];
    float scx = (ax1 + ax2) * 0.5f, scy = (ay1 + ay2) * 0.5f;
    float sw = ax2 - ax1, sh = ay2 - ay1;
    float dcx = (G.x + G.z) * 0.5f, dcy = (G.y + G.w) * 0.5f;
    float dw = G.z - G.x, dh = G.w - G.y;
    float t0 = (scx - dcx) / dw;
    float t1 = (scy - dcy) / dh;
    float t2 = logf(sw / dw);
    float t3 = logf(sh / dh);

    float4 d = ((const float4*)deltas)[a];
    float cx = d.x * sw + scx, cy = d.y * sh + scy;
    float w = expf(d.z) * sw, h = expf(d.w) * sh;
    float r0 = fminf(fmaxf(cx - 0.5f * w, 0.0f), IMGSZ);
    float r1 = fminf(fmaxf(cy - 0.5f * h, 0.0f), IMGSZ);
    float r2 = fminf(fmaxf(cx + 0.5f * w, 0.0f), IMGSZ);
    float r3 = fminf(fmaxf(cy + 0.5f * h, 0.0f), IMGSZ);

    float* row = out + (size_t)a * 9;
    row[0] = t0; row[1] = t1; row[2] = t2; row[3] = t3;
    row[4] = r0; row[5] = r1; row[6] = r2; row[7] = r3;
    row[8] = best;

    float sc = scores[a];
    unsigned int b = __float_as_uint(sc);
    unsigned int m = (b & 0x80000000u) ? ~b : (b | 0x80000000u);  // monotone map
    keys[a] = ((unsigned long long)m << 32) | (unsigned long long)(0xFFFFFFFFu - (unsigned int)a);
    int bin = (int)(sc * (float)NBINS);
    bin = bin < 0 ? 0 : (bin > NBINS - 1 ? NBINS - 1 : bin);
    atomicAdd(&hist[bin], 1u);
}

// 64-lane parallel suffix-scan over histogram bins (descending), ballot pick.
__global__ __launch_bounds__(64) void k_findbin(const unsigned int* __restrict__ hist,
                                                unsigned int* __restrict__ ctr) {
    int lane = threadIdx.x;
    unsigned int cum = 0;
    for (int c = 0; c < 64; ++c) {
        int bin = NBINS - 1 - c * 64 - lane;   // lane 0 = highest bin of chunk
        unsigned int v = hist[bin];
        unsigned int s = v;
        #pragma unroll
        for (int d = 1; d < 64; d <<= 1) {
            unsigned int t = __shfl_up(s, d, 64);
            if (lane >= d) s += t;
        }
        unsigned long long ball = __ballot(cum + s >= (unsigned int)KNMS);
        if (ball) {
            int L = __builtin_ctzll(ball);
            if (lane == 0) ctr[1] = (unsigned int)(NBINS - 1 - c * 64 - L);
            return;
        }
        cum += __shfl(s, 63, 64);
    }
    if (lane == 0) ctr[1] = 0u;  // fallback: everything passes
}

__global__ __launch_bounds__(256) void k_compact(
    const float* __restrict__ scores, const unsigned long long* __restrict__ keys,
    unsigned int* __restrict__ ctr, unsigned long long* __restrict__ buf)
{
    int a = blockIdx.x * 256 + threadIdx.x;
    if (a >= NA) return;
    float sc = scores[a];
    int bin = (int)(sc * (float)NBINS);
    bin = bin < 0 ? 0 : (bin > NBINS - 1 ? NBINS - 1 : bin);
    if ((unsigned int)bin >= ctr[1]) {
        unsigned int p = atomicAdd(&ctr[0], 1u);
        if (p < CMAX) buf[p] = keys[a];
    }
}

__global__ __launch_bounds__(1024) void k_sort(
    const unsigned int* __restrict__ ctr, const unsigned long long* __restrict__ buf,
    const float* __restrict__ out, float4* __restrict__ cand)
{
    __shared__ unsigned long long A[CMAX];
    unsigned int M = ctr[0] < (unsigned int)CMAX ? ctr[0] : (unsigned int)CMAX;
    int tid = threadIdx.x;
    for (int i = tid; i < CMAX; i += 1024) A[i] = (i < (int)M) ? buf[i] : 0ull;
    __syncthreads();

    // bitonic sort, DESCENDING (real keys all >= 2^63 > pad 0)
    for (int k = 2; k <= CMAX; k <<= 1) {
        for (int j = k >> 1; j > 0; j >>= 1) {
            for (int e = tid; e < CMAX; e += 1024) {
                int p = e ^ j;
                if (p > e) {
                    unsigned long long x = A[e], y = A[p];
                    bool up = ((e & k) == 0);
                    bool sw = up ? (x < y) : (x > y);
                    if (sw) { A[e] = y; A[p] = x; }
                }
            }
            __syncthreads();
        }
    }

    for (int i = tid; i < RPAD; i += 1024) {
        float4 c = make_float4(0.0f, 0.0f, 0.0f, 0.0f);
        if (i < KNMS && i < (int)M) {
            unsigned int idx = 0xFFFFFFFFu - (unsigned int)(A[i] & 0xFFFFFFFFull);
            const float* row = out + (size_t)idx * 9;
            c = make_float4(row[4], row[5], row[6], row[7]);
        }
        cand[i] = c;
    }
}

__global__ __launch_bounds__(64) void k_mask(
    const float4* __restrict__ cand, unsigned long long* __restrict__ mask)
{
    int rowChunk = blockIdx.x;   // 0..31
    int colChunk = blockIdx.y;   // 0..31
    __shared__ float4 cb[64];
    int t = threadIdx.x;
    cb[t] = cand[colChunk * 64 + t];
    __syncthreads();

    int r = rowChunk * 64 + t;
    unsigned long long m = 0ull;
    if (r < KNMS) {
        float4 R = cand[r];
        float areaR = (R.z - R.x) * (R.w - R.y);
        #pragma unroll 8
        for (int c = 0; c < 64; ++c) {
            int col = colChunk * 64 + c;
            if (col < KNMS && col > r) {
                float4 C = cb[c];
                float areaC = (C.z - C.x) * (C.w - C.y);
                float lx = fmaxf(R.x, C.x), ly = fmaxf(R.y, C.y);
                float rx = fminf(R.z, C.z), ry = fminf(R.w, C.w);
                float iw = fmaxf(rx - lx, 0.0f), ih = fmaxf(ry - ly, 0.0f);
                float inter = iw * ih;
                float iou = inter / (areaR + areaC - inter);
                if (iou > 0.7f) m |= (1ull << c);
            }
        }
    }
    // nontemporal: avoid leaving dirty lines scattered across 8 XCDs' L2s --
    // k_nms (single CU) reads this data next.
    __builtin_nontemporal_store(m, &mask[(size_t)r * 32 + colChunk]);
}

// Serial NMS, LDS-pipelined, zero per-row cross-lane ops.
//  - 3-slot LDS ring staged 3 blocks ahead via global_load_lds (counted vmcnt)
//  - per-row diagonal word re-read from LDS at a wave-uniform address (broadcast)
//  - cur (suppression word of current block) is replicated-uniform in VGPRs;
//    bit p of cur is final before row p is processed, so kept = ~cur_final
//  - remv (global suppression, lane l owns u32 word l) ORs in kept rows' masks
//    reusing the chain's sel; snapshot per block needs only 2 readlanes.
__global__ __launch_bounds__(64) void k_nms(
    const unsigned int* __restrict__ mask32, float* __restrict__ keep_out)
{
    __shared__ unsigned int S[3][64 * 64];   // 3 x 16KB ring
    const int lane = threadIdx.x;

#define STAGE(blk, slot_) do {                                                  \
        const char* gsrc = (const char*)mask32 + (size_t)(blk) * 16384 + lane * 16; \
        _Pragma("unroll")                                                       \
        for (int i_ = 0; i_ < 16; ++i_)                                         \
            __builtin_amdgcn_global_load_lds(                                   \
                (const unsigned int*)(gsrc + i_ * 1024),                        \
                &S[slot_][i_ * 256], 16, 0, 0);                                 \
    } while (0)

    STAGE(0, 0); STAGE(1, 1); STAGE(2, 2);

    unsigned int remv = 0u;

    for (int b = 0; b < 32; ++b) {
        const int slot = b % 3;
        if (b < 30)       asm volatile("s_waitcnt vmcnt(32)" ::: "memory");
        else if (b == 30) asm volatile("s_waitcnt vmcnt(16)" ::: "memory");
        else              asm volatile("s_waitcnt vmcnt(0)"  ::: "memory");
        __builtin_amdgcn_sched_barrier(0);

        const unsigned int* Sb = &S[slot][0];

        unsigned int cur_lo = (unsigned int)__builtin_amdgcn_readlane((int)remv, 2 * b);
        unsigned int cur_hi = (unsigned int)__builtin_amdgcn_readlane((int)remv, 2 * b + 1);

        unsigned int Dl[2][16], Dh[2][16], Wv[2][16];
        #pragma unroll
        for (int j = 0; j < 16; ++j) {
            uint2 d = *(const uint2*)&Sb[j * 64 + 2 * b];   // uniform addr -> broadcast
            Dl[0][j] = d.x; Dh[0][j] = d.y;
            Wv[0][j] = Sb[j * 64 + lane];
        }

        #pragma unroll
        for (int q = 0; q < 4; ++q) {
            const int pq = q & 1, nq = pq ^ 1;
            if (q < 3) {
                #pragma unroll
                for (int j = 0; j < 16; ++j) {
                    int r = (q + 1) * 16 + j;
                    uint2 d = *(const uint2*)&Sb[r * 64 + 2 * b];
                    Dl[nq][j] = d.x; Dh[nq][j] = d.y;
                    Wv[nq][j] = Sb[r * 64 + lane];
                }
            }
            #pragma unroll
            for (int j = 0; j < 16; ++j) {
                const int r = q * 16 + j;
                unsigned int t = (q < 2) ? ((cur_lo >> r) & 1u)
                                         : ((cur_hi >> (r - 32)) & 1u);
                unsigned int sel = t - 1u;       // kept -> 0xFFFFFFFF
                cur_lo |= Dl[pq][j] & sel;
                cur_hi |= Dh[pq][j] & sel;
                remv   |= Wv[pq][j] & sel;
            }
        }

        int row = b * 64 + lane;
        if (row < KNMS) {
            unsigned long long curq = ((unsigned long long)cur_hi << 32) | cur_lo;
            keep_out[row] = ((curq >> lane) & 1ull) ? 0.0f : 1.0f;
        }

        __builtin_amdgcn_sched_barrier(0);
        if (b + 3 < 32) STAGE(b + 3, slot);
    }
#undef STAGE
}

extern "C" void kernel_launch(void* const* d_in, const int* in_sizes, int n_in,
                              void* d_out, int out_size, void* d_ws, size_t ws_size,
                              hipStream_t stream) {
    const float* true_bx = (const float*)d_in[2];
    const float* deltas  = (const float*)d_in[3];
    const float* scores  = (const float*)d_in[4];
    float* out = (float*)d_out;

    char* ws = (char*)d_ws;
    unsigned long long* keys = (unsigned long long*)(ws + 0);
    unsigned int*       hist = (unsigned int*)(ws + 720000);
    unsigned int*       ctr  = (unsigned int*)(ws + 736384);
    unsigned long long* buf  = (unsigned long long*)(ws + 736400);
    float4*             cand = (float4*)(ws + 769168);
    unsigned long long* mask = (unsigned long long*)(ws + 801936);
    unsigned int*       mask32 = (unsigned int*)(ws + 801936);

    hipLaunchKernelGGL(k_zero, dim3(16), dim3(256), 0, stream, hist, ctr);
    hipLaunchKernelGGL(k_prep, dim3((NA + 255) / 256), dim3(256), 0, stream,
                       true_bx, deltas, scores, out, keys, hist);
    hipLaunchKernelGGL(k_findbin, dim3(1), dim3(64), 0, stream, hist, ctr);
    hipLaunchKernelGGL(k_compact, dim3((NA + 255) / 256), dim3(256), 0, stream,
                       scores, keys, ctr, buf);
    hipLaunchKernelGGL(k_sort, dim3(1), dim3(1024), 0, stream, ctr, buf, out, cand);
    hipLaunchKernelGGL(k_mask, dim3(32, 32), dim3(64), 0, stream, cand, mask);
    hipLaunchKernelGGL(k_nms, dim3(1), dim3(64), 0, stream, mask32, out + (size_t)NA * 9);
}

// Round 6
// 146.850 us; speedup vs baseline: 1.3292x; 1.2441x over previous
//
#include <hip/hip_runtime.h>
#include <hip/hip_bf16.h>

#define NA    90000
#define NGT   256
#define KNMS  2000
#define RPAD  2048          // padded NMS rows (multiple of 64)
#define NBINS 4096
#define CMAX  4096          // compact buffer capacity
#define IMGSZ 1600.0f

// ---------------- ws layout (bytes) ----------------
// keys  : 0        .. 720000   (u64[90000])
// hist  : 720000   .. 736384   (u32[4096])
// ctr   : 736384   .. 736400   (u32[4])   [0]=compact count, [1]=bin B
// buf   : 736400   .. 769168   (u64[4096])
// cand  : 769168   .. 801936   (float4[2048])
// mask  : 801936   .. 1326224  (u64[2048*32] == u32[2048*64] little-endian)

__device__ __forceinline__ float4 compute_local(int k) {
    const float ratios[3] = {0.5f, 1.0f, 2.0f};
    const float scales[3] = {8.0f, 16.0f, 32.0f};
    int r = k / 3, sc = k % 3;
    float b0 = 0.0f, b1 = 0.0f, b2 = 15.0f, b3 = 15.0f;
    float y0 = b0 + 0.5f * (b3 - 1.0f);
    float y1 = b1 + 0.5f * (b2 - 1.0f);
    float y2 = b3 - b1 + 1.0f;
    float y3 = b2 - b0 + 1.0f;
    float wr = rintf(sqrtf(y2 * y3 / ratios[r]));   // jnp.round = half-even = rintf
    float hr = rintf(wr * ratios[r]);
    float a0 = y0 - 0.5f * (wr - 1.0f);
    float a1 = y1 - 0.5f * (hr - 1.0f);
    float a2 = y0 + 0.5f * (wr - 1.0f);
    float a3 = y1 + 0.5f * (hr - 1.0f);
    float ya0 = a0 + 0.5f * (a3 - 1.0f);
    float ya1 = a1 + 0.5f * (a2 - 1.0f);
    float ya2 = a3 - a1 + 1.0f;
    float ya3 = a2 - a0 + 1.0f;
    float w = ya2 * scales[sc];
    float h = ya3 * scales[sc];
    float4 o;
    o.x = ya0 - 0.5f * (w - 1.0f);
    o.y = ya1 - 0.5f * (h - 1.0f);
    o.z = ya0 + 0.5f * (w - 1.0f);
    o.w = ya1 + 0.5f * (h - 1.0f);
    return o;
}

__global__ void k_zero(unsigned int* __restrict__ hist, unsigned int* __restrict__ ctr) {
    int i = blockIdx.x * 256 + threadIdx.x;
    if (i < NBINS) hist[i] = 0u;
    if (i < 4) ctr[i] = 0u;
}

__global__ __launch_bounds__(256) void k_prep(
    const float* __restrict__ true_bx, const float* __restrict__ deltas,
    const float* __restrict__ scores, float* __restrict__ out,
    unsigned long long* __restrict__ keys, unsigned int* __restrict__ hist)
{
    __shared__ float4 gt[NGT];
    int tid = threadIdx.x;
    for (int i = tid; i < NGT; i += 256) gt[i] = ((const float4*)true_bx)[i];
    __syncthreads();

    int a = blockIdx.x * 256 + tid;
    if (a >= NA) return;

    int k  = a % 9;
    int s  = a / 9;
    int ix = s % 100;
    int iy = s / 100;

    float4 loc = compute_local(k);
    float sxv = (float)ix * 16.0f, syv = (float)iy * 16.0f;
    float ax1 = fminf(fmaxf(loc.x + sxv, 0.0f), IMGSZ);
    float ay1 = fminf(fmaxf(loc.y + syv, 0.0f), IMGSZ);
    float ax2 = fminf(fmaxf(loc.z + sxv, 0.0f), IMGSZ);
    float ay2 = fminf(fmaxf(loc.w + syv, 0.0f), IMGSZ);
    float areaA = (ax2 - ax1) * (ay2 - ay1);

    // argmax over 256 GTs, strict > keeps FIRST max (jnp.argmax semantics)
    float best = -1.0f; int bidx = 0;
    #pragma unroll 4
    for (int g = 0; g < NGT; ++g) {
        float4 G = gt[g];
        float areaG = (G.z - G.x) * (G.w - G.y);
        float lx = fmaxf(G.x, ax1), ly = fmaxf(G.y, ay1);
        float rx = fminf(G.z, ax2), ry = fminf(G.w, ay2);
        float iw = fmaxf(rx - lx, 0.0f), ih = fmaxf(ry - ly, 0.0f);
        float inter = iw * ih;
        float iou = inter / (areaG + areaA - inter);
        if (iou > best) { best = iou; bidx = g; }
    }

    float4 G = gt[bidx];
    float scx = (ax1 + ax2) * 0.5f, scy = (ay1 + ay2) * 0.5f;
    float sw = ax2 - ax1, sh = ay2 - ay1;
    float dcx = (G.x + G.z) * 0.5f, dcy = (G.y + G.w) * 0.5f;
    float dw = G.z - G.x, dh = G.w - G.y;
    float t0 = (scx - dcx) / dw;
    float t1 = (scy - dcy) / dh;
    float t2 = logf(sw / dw);
    float t3 = logf(sh / dh);

    float4 d = ((const float4*)deltas)[a];
    float cx = d.x * sw + scx, cy = d.y * sh + scy;
    float w = expf(d.z) * sw, h = expf(d.w) * sh;
    float r0 = fminf(fmaxf(cx - 0.5f * w, 0.0f), IMGSZ);
    float r1 = fminf(fmaxf(cy - 0.5f * h, 0.0f), IMGSZ);
    float r2 = fminf(fmaxf(cx + 0.5f * w, 0.0f), IMGSZ);
    float r3 = fminf(fmaxf(cy + 0.5f * h, 0.0f), IMGSZ);

    float* row = out + (size_t)a * 9;
    row[0] = t0; row[1] = t1; row[2] = t2; row[3] = t3;
    row[4] = r0; row[5] = r1; row[6] = r2; row[7] = r3;
    row[8] = best;

    float sc = scores[a];
    unsigned int b = __float_as_uint(sc);
    unsigned int m = (b & 0x80000000u) ? ~b : (b | 0x80000000u);  // monotone map
    keys[a] = ((unsigned long long)m << 32) | (unsigned long long)(0xFFFFFFFFu - (unsigned int)a);
    int bin = (int)(sc * (float)NBINS);
    bin = bin < 0 ? 0 : (bin > NBINS - 1 ? NBINS - 1 : bin);
    atomicAdd(&hist[bin], 1u);
}

// 64-lane parallel suffix-scan over histogram bins (descending), ballot pick.
__global__ __launch_bounds__(64) void k_findbin(const unsigned int* __restrict__ hist,
                                                unsigned int* __restrict__ ctr) {
    int lane = threadIdx.x;
    unsigned int cum = 0;
    for (int c = 0; c < 64; ++c) {
        int bin = NBINS - 1 - c * 64 - lane;   // lane 0 = highest bin of chunk
        unsigned int v = hist[bin];
        unsigned int s = v;
        #pragma unroll
        for (int d = 1; d < 64; d <<= 1) {
            unsigned int t = __shfl_up(s, d, 64);
            if (lane >= d) s += t;
        }
        unsigned long long ball = __ballot(cum + s >= (unsigned int)KNMS);
        if (ball) {
            int L = __builtin_ctzll(ball);
            if (lane == 0) ctr[1] = (unsigned int)(NBINS - 1 - c * 64 - L);
            return;
        }
        cum += __shfl(s, 63, 64);
    }
    if (lane == 0) ctr[1] = 0u;  // fallback: everything passes
}

__global__ __launch_bounds__(256) void k_compact(
    const float* __restrict__ scores, const unsigned long long* __restrict__ keys,
    unsigned int* __restrict__ ctr, unsigned long long* __restrict__ buf)
{
    int a = blockIdx.x * 256 + threadIdx.x;
    if (a >= NA) return;
    float sc = scores[a];
    int bin = (int)(sc * (float)NBINS);
    bin = bin < 0 ? 0 : (bin > NBINS - 1 ? NBINS - 1 : bin);
    if ((unsigned int)bin >= ctr[1]) {
        unsigned int p = atomicAdd(&ctr[0], 1u);
        if (p < CMAX) buf[p] = keys[a];
    }
}

// Enumeration (rank) scatter replaces the bitonic sort: keys are unique, so
// sorted position = #{keys greater than mine}. Uniform-address LDS broadcast
// scan, no barriers after the initial load, 16 blocks run on 16 CUs.
// Rank-scatter is independent of buf's (nondeterministic) compaction order.
__global__ __launch_bounds__(256) void k_rank(
    const unsigned int* __restrict__ ctr, const unsigned long long* __restrict__ buf,
    const float* __restrict__ out, float4* __restrict__ cand)
{
    __shared__ unsigned long long S[CMAX];
    const int tid = threadIdx.x;
    unsigned int M = ctr[0];
    if (M > (unsigned int)CMAX) M = CMAX;
    for (int i = tid; i < CMAX; i += 256) S[i] = (i < (int)M) ? buf[i] : 0ull;
    __syncthreads();

    const int me = blockIdx.x * 256 + tid;          // candidate slot
    const unsigned long long my = (me < (int)M) ? S[me] : 0ull;
    const int M4 = ((int)M + 3) & ~3;               // pad entries are 0, never > a real key
    int r0 = 0, r1 = 0;
    for (int i = 0; i < M4; i += 4) {
        unsigned long long k0 = S[i], k1 = S[i + 1], k2 = S[i + 2], k3 = S[i + 3];
        r0 += (k0 > my); r1 += (k1 > my);
        r0 += (k2 > my); r1 += (k3 > my);
    }
    const int rank = r0 + r1;
    if (me < (int)M && rank < KNMS) {
        unsigned int idx = 0xFFFFFFFFu - (unsigned int)(my & 0xFFFFFFFFull);
        const float* row = out + (size_t)idx * 9;
        cand[rank] = make_float4(row[4], row[5], row[6], row[7]);
    }
}

__global__ __launch_bounds__(64) void k_mask(
    const float4* __restrict__ cand, unsigned long long* __restrict__ mask)
{
    int rowChunk = blockIdx.x;   // 0..31
    int colChunk = blockIdx.y;   // 0..31
    __shared__ float4 cb[64];
    int t = threadIdx.x;
    cb[t] = cand[colChunk * 64 + t];
    __syncthreads();

    int r = rowChunk * 64 + t;
    unsigned long long m = 0ull;
    if (r < KNMS) {
        float4 R = cand[r];
        float areaR = (R.z - R.x) * (R.w - R.y);
        #pragma unroll 8
        for (int c = 0; c < 64; ++c) {
            int col = colChunk * 64 + c;
            if (col < KNMS && col > r) {
                float4 C = cb[c];
                float areaC = (C.z - C.x) * (C.w - C.y);
                float lx = fmaxf(R.x, C.x), ly = fmaxf(R.y, C.y);
                float rx = fminf(R.z, C.z), ry = fminf(R.w, C.w);
                float iw = fmaxf(rx - lx, 0.0f), ih = fmaxf(ry - ly, 0.0f);
                float inter = iw * ih;
                float iou = inter / (areaR + areaC - inter);
                if (iou > 0.7f) m |= (1ull << c);
            }
        }
    }
    // nontemporal: avoid leaving dirty lines scattered across 8 XCDs' L2s --
    // k_nms (single CU) reads this data next.
    __builtin_nontemporal_store(m, &mask[(size_t)r * 32 + colChunk]);
}

// Serial NMS, LDS-pipelined, zero per-row cross-lane ops.
//  - 3-slot LDS ring staged 3 blocks ahead via global_load_lds (counted vmcnt)
//  - per-row diagonal word re-read from LDS at a wave-uniform address (broadcast)
//  - cur (suppression word of current block) is replicated-uniform in VGPRs;
//    bit p of cur is final before row p is processed, so kept = ~cur_final
//  - remv (global suppression, lane l owns u32 word l) ORs in kept rows' masks
//    reusing the chain's sel; snapshot per block needs only 2 readlanes.
__global__ __launch_bounds__(64) void k_nms(
    const unsigned int* __restrict__ mask32, float* __restrict__ keep_out)
{
    __shared__ unsigned int S[3][64 * 64];   // 3 x 16KB ring
    const int lane = threadIdx.x;

#define STAGE(blk, slot_) do {                                                  \
        const char* gsrc = (const char*)mask32 + (size_t)(blk) * 16384 + lane * 16; \
        _Pragma("unroll")                                                       \
        for (int i_ = 0; i_ < 16; ++i_)                                         \
            __builtin_amdgcn_global_load_lds(                                   \
                (const unsigned int*)(gsrc + i_ * 1024),                        \
                &S[slot_][i_ * 256], 16, 0, 0);                                 \
    } while (0)

    STAGE(0, 0); STAGE(1, 1); STAGE(2, 2);

    unsigned int remv = 0u;

    for (int b = 0; b < 32; ++b) {
        const int slot = b % 3;
        if (b < 30)       asm volatile("s_waitcnt vmcnt(32)" ::: "memory");
        else if (b == 30) asm volatile("s_waitcnt vmcnt(16)" ::: "memory");
        else              asm volatile("s_waitcnt vmcnt(0)"  ::: "memory");
        __builtin_amdgcn_sched_barrier(0);

        const unsigned int* Sb = &S[slot][0];

        unsigned int cur_lo = (unsigned int)__builtin_amdgcn_readlane((int)remv, 2 * b);
        unsigned int cur_hi = (unsigned int)__builtin_amdgcn_readlane((int)remv, 2 * b + 1);

        unsigned int Dl[2][16], Dh[2][16], Wv[2][16];
        #pragma unroll
        for (int j = 0; j < 16; ++j) {
            uint2 d = *(const uint2*)&Sb[j * 64 + 2 * b];   // uniform addr -> broadcast
            Dl[0][j] = d.x; Dh[0][j] = d.y;
            Wv[0][j] = Sb[j * 64 + lane];
        }

        #pragma unroll
        for (int q = 0; q < 4; ++q) {
            const int pq = q & 1, nq = pq ^ 1;
            if (q < 3) {
                #pragma unroll
                for (int j = 0; j < 16; ++j) {
                    int r = (q + 1) * 16 + j;
                    uint2 d = *(const uint2*)&Sb[r * 64 + 2 * b];
                    Dl[nq][j] = d.x; Dh[nq][j] = d.y;
                    Wv[nq][j] = Sb[r * 64 + lane];
                }
            }
            #pragma unroll
            for (int j = 0; j < 16; ++j) {
                const int r = q * 16 + j;
                unsigned int t = (q < 2) ? ((cur_lo >> r) & 1u)
                                         : ((cur_hi >> (r - 32)) & 1u);
                unsigned int sel = t - 1u;       // kept -> 0xFFFFFFFF
                cur_lo |= Dl[pq][j] & sel;
                cur_hi |= Dh[pq][j] & sel;
                remv   |= Wv[pq][j] & sel;
            }
        }

        int row = b * 64 + lane;
        if (row < KNMS) {
            unsigned long long curq = ((unsigned long long)cur_hi << 32) | cur_lo;
            keep_out[row] = ((curq >> lane) & 1ull) ? 0.0f : 1.0f;
        }

        __builtin_amdgcn_sched_barrier(0);
        if (b + 3 < 32) STAGE(b + 3, slot);
    }
#undef STAGE
}

extern "C" void kernel_launch(void* const* d_in, const int* in_sizes, int n_in,
                              void* d_out, int out_size, void* d_ws, size_t ws_size,
                              hipStream_t stream) {
    const float* true_bx = (const float*)d_in[2];
    const float* deltas  = (const float*)d_in[3];
    const float* scores  = (const float*)d_in[4];
    float* out = (float*)d_out;

    char* ws = (char*)d_ws;
    unsigned long long* keys = (unsigned long long*)(ws + 0);
    unsigned int*       hist = (unsigned int*)(ws + 720000);
    unsigned int*       ctr  = (unsigned int*)(ws + 736384);
    unsigned long long* buf  = (unsigned long long*)(ws + 736400);
    float4*             cand = (float4*)(ws + 769168);
    unsigned long long* mask = (unsigned long long*)(ws + 801936);
    unsigned int*       mask32 = (unsigned int*)(ws + 801936);

    hipLaunchKernelGGL(k_zero, dim3(16), dim3(256), 0, stream, hist, ctr);
    hipLaunchKernelGGL(k_prep, dim3((NA + 255) / 256), dim3(256), 0, stream,
                       true_bx, deltas, scores, out, keys, hist);
    hipLaunchKernelGGL(k_findbin, dim3(1), dim3(64), 0, stream, hist, ctr);
    hipLaunchKernelGGL(k_compact, dim3((NA + 255) / 256), dim3(256), 0, stream,
                       scores, keys, ctr, buf);
    hipLaunchKernelGGL(k_rank, dim3(CMAX / 256), dim3(256), 0, stream, ctr, buf, out, cand);
    hipLaunchKernelGGL(k_mask, dim3(32, 32), dim3(64), 0, stream, cand, mask);
    hipLaunchKernelGGL(k_nms, dim3(1), dim3(64), 0, stream, mask32, out + (size_t)NA * 9);
}

// Round 7
// 144.850 us; speedup vs baseline: 1.3476x; 1.0138x over previous
//
#include <hip/hip_runtime.h>
#include <hip/hip_bf16.h>

#define NA    90000
#define NGT   256
#define KNMS  2000
#define RPAD  2048          // padded NMS rows (multiple of 64)
#define NBINS 4096
#define CMAX  4096          // compact buffer capacity
#define IMGSZ 1600.0f

// ---------------- ws layout (bytes) ----------------
// keys  : 0        .. 720000   (u64[90000])
// hist  : 720000   .. 736384   (u32[4096])
// ctr   : 736384   .. 736400   (u32[4])   [0]=compact count, [1]=bin B
// buf   : 736400   .. 769168   (u64[4096])
// cand  : 769168   .. 801936   (float4[2048])
// mask  : 801936   .. 1326224  (u64[2048*32] == u32[2048*64] little-endian)

__device__ __forceinline__ float4 compute_local(int k) {
    const float ratios[3] = {0.5f, 1.0f, 2.0f};
    const float scales[3] = {8.0f, 16.0f, 32.0f};
    int r = k / 3, sc = k % 3;
    float b0 = 0.0f, b1 = 0.0f, b2 = 15.0f, b3 = 15.0f;
    float y0 = b0 + 0.5f * (b3 - 1.0f);
    float y1 = b1 + 0.5f * (b2 - 1.0f);
    float y2 = b3 - b1 + 1.0f;
    float y3 = b2 - b0 + 1.0f;
    float wr = rintf(sqrtf(y2 * y3 / ratios[r]));   // jnp.round = half-even = rintf
    float hr = rintf(wr * ratios[r]);
    float a0 = y0 - 0.5f * (wr - 1.0f);
    float a1 = y1 - 0.5f * (hr - 1.0f);
    float a2 = y0 + 0.5f * (wr - 1.0f);
    float a3 = y1 + 0.5f * (hr - 1.0f);
    float ya0 = a0 + 0.5f * (a3 - 1.0f);
    float ya1 = a1 + 0.5f * (a2 - 1.0f);
    float ya2 = a3 - a1 + 1.0f;
    float ya3 = a2 - a0 + 1.0f;
    float w = ya2 * scales[sc];
    float h = ya3 * scales[sc];
    float4 o;
    o.x = ya0 - 0.5f * (w - 1.0f);
    o.y = ya1 - 0.5f * (h - 1.0f);
    o.z = ya0 + 0.5f * (w - 1.0f);
    o.w = ya1 + 0.5f * (h - 1.0f);
    return o;
}

__global__ void k_zero(unsigned int* __restrict__ hist, unsigned int* __restrict__ ctr) {
    int i = blockIdx.x * 256 + threadIdx.x;
    if (i < NBINS) hist[i] = 0u;
    if (i < 4) ctr[i] = 0u;
}

__global__ __launch_bounds__(256) void k_prep(
    const float* __restrict__ true_bx, const float* __restrict__ deltas,
    const float* __restrict__ scores, float* __restrict__ out,
    unsigned long long* __restrict__ keys, unsigned int* __restrict__ hist)
{
    __shared__ float4 gt[NGT];
    int tid = threadIdx.x;
    for (int i = tid; i < NGT; i += 256) gt[i] = ((const float4*)true_bx)[i];
    __syncthreads();

    int a = blockIdx.x * 256 + tid;
    if (a >= NA) return;

    int k  = a % 9;
    int s  = a / 9;
    int ix = s % 100;
    int iy = s / 100;

    float4 loc = compute_local(k);
    float sxv = (float)ix * 16.0f, syv = (float)iy * 16.0f;
    float ax1 = fminf(fmaxf(loc.x + sxv, 0.0f), IMGSZ);
    float ay1 = fminf(fmaxf(loc.y + syv, 0.0f), IMGSZ);
    float ax2 = fminf(fmaxf(loc.z + sxv, 0.0f), IMGSZ);
    float ay2 = fminf(fmaxf(loc.w + syv, 0.0f), IMGSZ);
    float areaA = (ax2 - ax1) * (ay2 - ay1);

    // argmax over 256 GTs, strict > keeps FIRST max (jnp.argmax semantics)
    float best = -1.0f; int bidx = 0;
    #pragma unroll 4
    for (int g = 0; g < NGT; ++g) {
        float4 G = gt[g];
        float areaG = (G.z - G.x) * (G.w - G.y);
        float lx = fmaxf(G.x, ax1), ly = fmaxf(G.y, ay1);
        float rx = fminf(G.z, ax2), ry = fminf(G.w, ay2);
        float iw = fmaxf(rx - lx, 0.0f), ih = fmaxf(ry - ly, 0.0f);
        float inter = iw * ih;
        float iou = inter / (areaG + areaA - inter);
        if (iou > best) { best = iou; bidx = g; }
    }

    float4 G = gt[bidx];
    float scx = (ax1 + ax2) * 0.5f, scy = (ay1 + ay2) * 0.5f;
    float sw = ax2 - ax1, sh = ay2 - ay1;
    float dcx = (G.x + G.z) * 0.5f, dcy = (G.y + G.w) * 0.5f;
    float dw = G.z - G.x, dh = G.w - G.y;
    float t0 = (scx - dcx) / dw;
    float t1 = (scy - dcy) / dh;
    float t2 = logf(sw / dw);
    float t3 = logf(sh / dh);

    float4 d = ((const float4*)deltas)[a];
    float cx = d.x * sw + scx, cy = d.y * sh + scy;
    float w = expf(d.z) * sw, h = expf(d.w) * sh;
    float r0 = fminf(fmaxf(cx - 0.5f * w, 0.0f), IMGSZ);
    float r1 = fminf(fmaxf(cy - 0.5f * h, 0.0f), IMGSZ);
    float r2 = fminf(fmaxf(cx + 0.5f * w, 0.0f), IMGSZ);
    float r3 = fminf(fmaxf(cy + 0.5f * h, 0.0f), IMGSZ);

    float* row = out + (size_t)a * 9;
    row[0] = t0; row[1] = t1; row[2] = t2; row[3] = t3;
    row[4] = r0; row[5] = r1; row[6] = r2; row[7] = r3;
    row[8] = best;

    float sc = scores[a];
    unsigned int b = __float_as_uint(sc);
    unsigned int m = (b & 0x80000000u) ? ~b : (b | 0x80000000u);  // monotone map
    keys[a] = ((unsigned long long)m << 32) | (unsigned long long)(0xFFFFFFFFu - (unsigned int)a);
    int bin = (int)(sc * (float)NBINS);
    bin = bin < 0 ? 0 : (bin > NBINS - 1 ? NBINS - 1 : bin);
    atomicAdd(&hist[bin], 1u);
}

// 64-lane parallel suffix-scan over histogram bins (descending), ballot pick.
__global__ __launch_bounds__(64) void k_findbin(const unsigned int* __restrict__ hist,
                                                unsigned int* __restrict__ ctr) {
    int lane = threadIdx.x;
    unsigned int cum = 0;
    for (int c = 0; c < 64; ++c) {
        int bin = NBINS - 1 - c * 64 - lane;   // lane 0 = highest bin of chunk
        unsigned int v = hist[bin];
        unsigned int s = v;
        #pragma unroll
        for (int d = 1; d < 64; d <<= 1) {
            unsigned int t = __shfl_up(s, d, 64);
            if (lane >= d) s += t;
        }
        unsigned long long ball = __ballot(cum + s >= (unsigned int)KNMS);
        if (ball) {
            int L = __builtin_ctzll(ball);
            if (lane == 0) ctr[1] = (unsigned int)(NBINS - 1 - c * 64 - L);
            return;
        }
        cum += __shfl(s, 63, 64);
    }
    if (lane == 0) ctr[1] = 0u;  // fallback: everything passes
}

__global__ __launch_bounds__(256) void k_compact(
    const float* __restrict__ scores, const unsigned long long* __restrict__ keys,
    unsigned int* __restrict__ ctr, unsigned long long* __restrict__ buf)
{
    int a = blockIdx.x * 256 + threadIdx.x;
    if (a >= NA) return;
    float sc = scores[a];
    int bin = (int)(sc * (float)NBINS);
    bin = bin < 0 ? 0 : (bin > NBINS - 1 ? NBINS - 1 : bin);
    if ((unsigned int)bin >= ctr[1]) {
        unsigned int p = atomicAdd(&ctr[0], 1u);
        if (p < CMAX) buf[p] = keys[a];
    }
}

// Enumeration (rank) scatter: keys unique -> sorted position = #{keys > mine}.
__global__ __launch_bounds__(256) void k_rank(
    const unsigned int* __restrict__ ctr, const unsigned long long* __restrict__ buf,
    const float* __restrict__ out, float4* __restrict__ cand)
{
    __shared__ unsigned long long S[CMAX];
    const int tid = threadIdx.x;
    unsigned int M = ctr[0];
    if (M > (unsigned int)CMAX) M = CMAX;
    for (int i = tid; i < CMAX; i += 256) S[i] = (i < (int)M) ? buf[i] : 0ull;
    __syncthreads();

    const int me = blockIdx.x * 256 + tid;          // candidate slot
    const unsigned long long my = (me < (int)M) ? S[me] : 0ull;
    const int M4 = ((int)M + 3) & ~3;               // pad entries are 0, never > a real key
    int r0 = 0, r1 = 0;
    for (int i = 0; i < M4; i += 4) {
        unsigned long long k0 = S[i], k1 = S[i + 1], k2 = S[i + 2], k3 = S[i + 3];
        r0 += (k0 > my); r1 += (k1 > my);
        r0 += (k2 > my); r1 += (k3 > my);
    }
    const int rank = r0 + r1;
    if (me < (int)M && rank < KNMS) {
        unsigned int idx = 0xFFFFFFFFu - (unsigned int)(my & 0xFFFFFFFFull);
        const float* row = out + (size_t)idx * 9;
        cand[rank] = make_float4(row[4], row[5], row[6], row[7]);
    }
}

__global__ __launch_bounds__(64) void k_mask(
    const float4* __restrict__ cand, unsigned long long* __restrict__ mask)
{
    int rowChunk = blockIdx.x;   // 0..31
    int colChunk = blockIdx.y;   // 0..31
    __shared__ float4 cb[64];
    int t = threadIdx.x;
    cb[t] = cand[colChunk * 64 + t];
    __syncthreads();

    int r = rowChunk * 64 + t;
    unsigned long long m = 0ull;
    if (r < KNMS) {
        float4 R = cand[r];
        float areaR = (R.z - R.x) * (R.w - R.y);
        #pragma unroll 8
        for (int c = 0; c < 64; ++c) {
            int col = colChunk * 64 + c;
            if (col < KNMS && col > r) {
                float4 C = cb[c];
                float areaC = (C.z - C.x) * (C.w - C.y);
                float lx = fmaxf(R.x, C.x), ly = fmaxf(R.y, C.y);
                float rx = fminf(R.z, C.z), ry = fminf(R.w, C.w);
                float iw = fmaxf(rx - lx, 0.0f), ih = fmaxf(ry - ly, 0.0f);
                float inter = iw * ih;
                float iou = inter / (areaR + areaC - inter);
                if (iou > 0.7f) m |= (1ull << c);
            }
        }
    }
    __builtin_nontemporal_store(m, &mask[(size_t)r * 32 + colChunk]);
}

// Producer/consumer serial NMS.
//   wave 0          : serial suppression chain, LDS-only reads, no vmcnt waits
//   waves 1..3      : staging engines -> 6-slot LDS ring via global_load_lds,
//                     handshake through volatile LDS flags (ready[slot], done)
// Consumer also prefetches the NEXT block's quarter 0 during the current
// block's quarter 3, so no LDS-latency is exposed at block boundaries.
__global__ __launch_bounds__(256) void k_nms(
    const unsigned int* __restrict__ mask32, float* __restrict__ keep_out)
{
    __shared__ unsigned int S[6][64 * 64];            // 96 KB ring
    __shared__ volatile unsigned int ready[8];        // staged block id + 1
    __shared__ volatile unsigned int done;            // consumer progress

    const int tid  = threadIdx.x;
    const int wave = tid >> 6;
    const int lane = tid & 63;

    if (tid == 0) { done = 0u; }
    if (tid < 8)  { ready[tid] = 0u; }
    __syncthreads();

    if (wave > 0) {
        // ---- stager: blocks b = wave-1, wave-1+3, ... ----
        for (int b = wave - 1; b < 32; b += 3) {
            const int slot = b % 6;
            // slot free when its previous occupant (b-6) has been consumed
            while ((int)done < b - 5) { __builtin_amdgcn_s_sleep(1); }
            asm volatile("" ::: "memory");
            const char* gsrc = (const char*)mask32 + (size_t)b * 16384 + lane * 16;
            #pragma unroll
            for (int i = 0; i < 16; ++i)
                __builtin_amdgcn_global_load_lds(
                    (const unsigned int*)(gsrc + i * 1024),
                    (unsigned int*)&S[slot][i * 256], 16, 0, 0);
            asm volatile("s_waitcnt vmcnt(0)" ::: "memory");
            if (lane == 0) ready[slot] = (unsigned int)(b + 1);
        }
        return;
    }

    // ---- consumer (wave 0) ----
#define POLL(bb) do {                                                          \
        while (ready[(bb) % 6] != (unsigned int)((bb) + 1)) {                  \
            __builtin_amdgcn_s_sleep(1);                                       \
        }                                                                      \
        asm volatile("" ::: "memory");                                         \
        __builtin_amdgcn_sched_barrier(0);                                     \
    } while (0)

    unsigned int remv = 0u;
    unsigned int Dl[2][16], Dh[2][16], Wv[2][16];

    // load quarter [row0..row0+15] of ring slot `sp` (diag col pair dcol) into buffer t
#define LOADQ(t, sp, dcol, row0) do {                                          \
        const unsigned int* Sb_ = &S[sp][0];                                   \
        _Pragma("unroll")                                                      \
        for (int j_ = 0; j_ < 16; ++j_) {                                      \
            uint2 d_ = *(const uint2*)&Sb_[(row0 + j_) * 64 + (dcol)];         \
            Dl[t][j_] = d_.x; Dh[t][j_] = d_.y;                                \
            Wv[t][j_] = Sb_[(row0 + j_) * 64 + lane];                          \
        }                                                                      \
    } while (0)

    POLL(0);
    LOADQ(0, 0, 0, 0);   // block 0, quarter 0

    for (int b = 0; b < 32; ++b) {
        const int slot = b % 6;
        if (b < 31) POLL(b + 1);   // next block staged -> cross-block prefetch safe

        unsigned int cur_lo = (unsigned int)__builtin_amdgcn_readlane((int)remv, 2 * b);
        unsigned int cur_hi = (unsigned int)__builtin_amdgcn_readlane((int)remv, 2 * b + 1);

        #pragma unroll
        for (int q = 0; q < 4; ++q) {
            const int pq = q & 1, nq = pq ^ 1;
            if (q < 3) {
                LOADQ(nq, slot, 2 * b, (q + 1) * 16);
            } else if (b < 31) {
                LOADQ(nq, (b + 1) % 6, 2 * (b + 1), 0);
            }
            #pragma unroll
            for (int j = 0; j < 16; ++j) {
                const int r = q * 16 + j;
                unsigned int t = (q < 2) ? ((cur_lo >> r) & 1u)
                                         : ((cur_hi >> (r - 32)) & 1u);
                unsigned int sel = t - 1u;       // kept -> 0xFFFFFFFF
                cur_lo |= Dl[pq][j] & sel;
                cur_hi |= Dh[pq][j] & sel;
                remv   |= Wv[pq][j] & sel;
            }
        }

        int row = b * 64 + lane;
        if (row < KNMS) {
            unsigned long long curq = ((unsigned long long)cur_hi << 32) | cur_lo;
            keep_out[row] = ((curq >> lane) & 1ull) ? 0.0f : 1.0f;
        }

        // free this slot for reuse (all our LDS reads for it are complete)
        asm volatile("s_waitcnt lgkmcnt(0)" ::: "memory");
        if (lane == 0) done = (unsigned int)(b + 1);
    }
#undef LOADQ
#undef POLL
}

extern "C" void kernel_launch(void* const* d_in, const int* in_sizes, int n_in,
                              void* d_out, int out_size, void* d_ws, size_t ws_size,
                              hipStream_t stream) {
    const float* true_bx = (const float*)d_in[2];
    const float* deltas  = (const float*)d_in[3];
    const float* scores  = (const float*)d_in[4];
    float* out = (float*)d_out;

    char* ws = (char*)d_ws;
    unsigned long long* keys = (unsigned long long*)(ws + 0);
    unsigned int*       hist = (unsigned int*)(ws + 720000);
    unsigned int*       ctr  = (unsigned int*)(ws + 736384);
    unsigned long long* buf  = (unsigned long long*)(ws + 736400);
    float4*             cand = (float4*)(ws + 769168);
    unsigned long long* mask = (unsigned long long*)(ws + 801936);
    unsigned int*       mask32 = (unsigned int*)(ws + 801936);

    hipLaunchKernelGGL(k_zero, dim3(16), dim3(256), 0, stream, hist, ctr);
    hipLaunchKernelGGL(k_prep, dim3((NA + 255) / 256), dim3(256), 0, stream,
                       true_bx, deltas, scores, out, keys, hist);
    hipLaunchKernelGGL(k_findbin, dim3(1), dim3(64), 0, stream, hist, ctr);
    hipLaunchKernelGGL(k_compact, dim3((NA + 255) / 256), dim3(256), 0, stream,
                       scores, keys, ctr, buf);
    hipLaunchKernelGGL(k_rank, dim3(CMAX / 256), dim3(256), 0, stream, ctr, buf, out, cand);
    hipLaunchKernelGGL(k_mask, dim3(32, 32), dim3(64), 0, stream, cand, mask);
    hipLaunchKernelGGL(k_nms, dim3(1), dim3(256), 0, stream, mask32, out + (size_t)NA * 9);
}